// Round 8
// baseline (331.603 us; speedup 1.0000x reference)
//
#include <hip/hip_runtime.h>

// (B,H,Lq,Lkv) = (2,32,2048,2048), KEEP_RATIO=0.5, SINK=4, RECENT=64, ALPHA=0.2
#define B_   2
#define H_   32
#define BH   64
#define LQ   2048
#define LKV  2048
#define SINKN   4
#define RECENTN 64
#define MID  1980                              // LKV - SINK - RECENT
#define TOTAL_BUDGET 30592                     // (1024-68)*32
#define MINB 198                               // int(1980*0.5*0.2)
#define QCH  32                                // blocks per bh
#define JW   495                               // MID/4, j-window per countmask block

typedef float float4n __attribute__((ext_vector_type(4)));  // true vector type for nontemporal builtin

// Native v_log_f32 (log2, ~2^-21 rel err).
static __device__ __forceinline__ float fast_log2(float x) {
#if defined(__has_builtin) && __has_builtin(__builtin_amdgcn_logf)
  return __builtin_amdgcn_logf(x);
#else
  float r; asm volatile("v_log_f32 %0, %1" : "=v"(r) : "v"(x)); return r;
#endif
}

// Streaming stats. ROLLING-WINDOW row order: the 32 blocks of one bh read rows
// q = qc + 32*it — at any instant they sweep ONE contiguous ~256KB window per
// bh (64 chip-wide coherent streams, like the 6.6TB/s fills) instead of 2048
// private slabs. Loads are nontemporal (input touched once; don't pollute L2/L3).
// f32 group-of-4-rows accumulation folded into f64, fixed order.
// Entropy = sum(w*log2(w+eps)); scaled by -ln2 in budget_kernel.
__global__ __launch_bounds__(256) void stats_kernel(const float* __restrict__ A,
                                                    double* __restrict__ spart,
                                                    double* __restrict__ epart) {
  const int qc = blockIdx.x;      // 0..QCH-1 (row phase)
  const int bh = blockIdx.y;      // 0..63
  const int t  = threadIdx.x;     // 0..255
  const float4n* __restrict__ p = reinterpret_cast<const float4n*>(
      A + (size_t)bh * LQ * LKV);

  double s0=0,s1=0,s2=0,s3=0,s4=0,s5=0,s6=0,s7=0,e=0;
  for (int g = 0; g < 16; ++g) {  // 16 groups x 4 rows = 64 rows per block
    float a0=0.f,a1=0.f,a2=0.f,a3=0.f,b0=0.f,b1=0.f,b2=0.f,b3=0.f,e0=0.f,e1=0.f;
#pragma unroll
    for (int r = 0; r < 4; ++r) {
      const size_t row = (size_t)qc + 32u * (4u * g + r);
      float4n w = __builtin_nontemporal_load(&p[row * 512 + t]);
      float4n v = __builtin_nontemporal_load(&p[row * 512 + 256 + t]);
      a0 += w.x; a1 += w.y; a2 += w.z; a3 += w.w;
      e0 = fmaf(w.x, fast_log2(w.x + 1e-8f), e0);
      e0 = fmaf(w.y, fast_log2(w.y + 1e-8f), e0);
      e0 = fmaf(w.z, fast_log2(w.z + 1e-8f), e0);
      e0 = fmaf(w.w, fast_log2(w.w + 1e-8f), e0);
      b0 += v.x; b1 += v.y; b2 += v.z; b3 += v.w;
      e1 = fmaf(v.x, fast_log2(v.x + 1e-8f), e1);
      e1 = fmaf(v.y, fast_log2(v.y + 1e-8f), e1);
      e1 = fmaf(v.z, fast_log2(v.z + 1e-8f), e1);
      e1 = fmaf(v.w, fast_log2(v.w + 1e-8f), e1);
    }
    s0 += (double)a0; s1 += (double)a1; s2 += (double)a2; s3 += (double)a3;
    s4 += (double)b0; s5 += (double)b1; s6 += (double)b2; s7 += (double)b3;
    e += (double)e0 + (double)e1;
  }
  double* sp = spart + (size_t)(qc * BH + bh) * LKV;
  const int c0 = 4 * t, c1 = 1024 + 4 * t;
  sp[c0] = s0; sp[c0 + 1] = s1; sp[c0 + 2] = s2; sp[c0 + 3] = s3;
  sp[c1] = s4; sp[c1 + 1] = s5; sp[c1 + 2] = s6; sp[c1 + 3] = s7;

  __shared__ double red[256];
  red[t] = e;
  __syncthreads();
  for (int off = 128; off > 0; off >>= 1) {
    if (t < off) red[t] += red[t + off];
    __syncthreads();
  }
  if (t == 0) epart[(size_t)bh * QCH + qc] = red[0];
}

// head_entropy -> budgets -> k per (b,h). Half-even rint, Python floor-div.
__global__ __launch_bounds__(64) void budget_kernel(const double* __restrict__ epart,
                                                    int* __restrict__ kvals) {
  __shared__ double he[BH];
  __shared__ int bud[H_];
  const int t = threadIdx.x;  // 0..63 = bh
  double s = 0.0;
  for (int p = 0; p < QCH; ++p) s += epart[(size_t)t * QCH + p];
  he[t] = (-0.6931471805599453 * s) / (double)LQ;
  __syncthreads();
  if (t == 0) {
    for (int b = 0; b < B_; ++b) {
      double S = 0.0;
      for (int h = 0; h < H_; ++h) S += he[b * H_ + h];
      S += 1e-8;
      long long sum = 0;
      for (int h = 0; h < H_; ++h) {
        double x = he[b * H_ + h] / S * (double)TOTAL_BUDGET;
        int v = (int)rint(x);
        if (v < MINB) v = MINB;
        bud[h] = v; sum += v;
      }
      long long diff = (long long)TOTAL_BUDGET - sum;
      long long ph = (diff >= 0) ? diff / H_ : -((-diff + H_ - 1) / H_);
      long long rem = diff - ph * H_;
      for (int h = 0; h < H_; ++h) {
        long long v = (long long)bud[h] + ph + ((h < rem) ? 1 : 0);
        if (v < 1) v = 1;
        if (v > MID) v = MID;
        kvals[b * H_ + h] = (int)v;
      }
    }
  }
}

// Fused reduce + stable-descending rank + threshold + mask write.
// Block (jc, bh), jc in 0..3: builds s[0..MID) in LDS (fixed-order f64 sum of
// the 32 spart partials; spart is 32MB -> L3-resident, 4x redundant read ~free),
// then each thread ranks up to 2 j-slots in its 495-wide window via a
// broadcast-only i-scan (same LDS addr across lanes -> conflict-free).
// rank(j) = #{i: s_i > s_j} + #{i<j: s_i == s_j}; keep iff rank < k.
__global__ __launch_bounds__(256) void countmask_kernel(const double* __restrict__ spart,
                                                        const int* __restrict__ kvals,
                                                        int* __restrict__ out) {
  const int jc = blockIdx.x, bh = blockIdx.y, t = threadIdx.x;
  __shared__ double s[MID];
  for (int m = t; m < MID; m += 256) {
    double v = 0.0;
    for (int qc = 0; qc < QCH; ++qc)
      v += spart[(size_t)(qc * BH + bh) * LKV + SINKN + m];
    s[m] = v;
  }
  __syncthreads();
  const int j0 = jc * JW + t;            // max 3*495+255 = 1740 < MID
  const int j1 = j0 + 256;               // valid if t < JW-256 = 239
  const bool has1 = (t < JW - 256);
  const double k0 = s[j0];
  const double k1 = has1 ? s[j1] : 0.0;
  unsigned c0 = 0, c1 = 0;
  for (int i = 0; i < MID; ++i) {
    const double si = s[i];
    c0 += (si > k0) ? 1u : 0u;
    c0 += ((si == k0) && (i < j0)) ? 1u : 0u;
    c1 += (si > k1) ? 1u : 0u;
    c1 += ((si == k1) && (i < j1)) ? 1u : 0u;
  }
  const unsigned k = (unsigned)kvals[bh];
  out[(size_t)bh * LKV + SINKN + j0] = (c0 < k) ? 1 : 0;
  if (has1) out[(size_t)bh * LKV + SINKN + j1] = (c1 < k) ? 1 : 0;
  if (jc == 0) {
    if (t < SINKN)   out[(size_t)bh * LKV + t] = 1;
    if (t < RECENTN) out[(size_t)bh * LKV + (LKV - RECENTN) + t] = 1;
  }
}

extern "C" void kernel_launch(void* const* d_in, const int* in_sizes, int n_in,
                              void* d_out, int out_size, void* d_ws, size_t ws_size,
                              hipStream_t stream) {
  const float* A = (const float*)d_in[0];
  int* out = (int*)d_out;

  // ws: spart[QCH*64*2048 f64]=32MB | epart[64*QCH f64] | kvals[64 int]
  double* spart = (double*)d_ws;
  double* epart = spart + (size_t)QCH * BH * LKV;
  int* kvals = (int*)(epart + (size_t)BH * QCH);

  stats_kernel<<<dim3(QCH, BH), 256, 0, stream>>>(A, spart, epart);
  budget_kernel<<<1, 64, 0, stream>>>(epart, kvals);
  countmask_kernel<<<dim3(4, BH), 256, 0, stream>>>(spart, kvals, out);
}

// Round 9
// 280.889 us; speedup vs baseline: 1.1805x; 1.1805x over previous
//
#include <hip/hip_runtime.h>

// (B,H,Lq,Lkv) = (2,32,2048,2048), KEEP_RATIO=0.5, SINK=4, RECENT=64, ALPHA=0.2
#define B_   2
#define H_   32
#define BH   64
#define LQ   2048
#define LKV  2048
#define SINKN   4
#define RECENTN 64
#define MID  1980                              // LKV - SINK - RECENT
#define TOTAL_BUDGET 30592                     // (1024-68)*32
#define MINB 198                               // int(1980*0.5*0.2)
#define QCH  4                                 // q-chunks (R2 best config)
#define KVCH 2
#define KVLEN (LKV / KVCH)                     // 1024 cols per block
#define QLEN (LQ / QCH)                        // 512 rows per block
#define JW   495                               // MID/4, j-window per countmask block

// Native v_log_f32 (log2, ~2^-21 rel err) — proven accuracy-safe in R3-R8.
static __device__ __forceinline__ float fast_log2(float x) {
#if defined(__has_builtin) && __has_builtin(__builtin_amdgcn_logf)
  return __builtin_amdgcn_logf(x);
#else
  float r; asm volatile("v_log_f32 %0, %1" : "=v"(r) : "v"(x)); return r;
#endif
}

// Stats pass: EXACT R2 configuration (measured best: 297us total).
// Block (kvc, qc, bh): 1024 cols x 512 rows; thread owns 4 cols (one float4).
// f32 group-of-16-rows accumulation folded into f64, fixed order -> deterministic.
// Entropy = sum(w*log2(w+eps)); scaled by -ln2 in budget_kernel.
__global__ __launch_bounds__(256) void stats_kernel(const float* __restrict__ A,
                                                    double* __restrict__ spart,
                                                    double* __restrict__ epart) {
  const int kvc = blockIdx.x;     // 0..KVCH-1
  const int qc  = blockIdx.y;     // 0..QCH-1
  const int bh  = blockIdx.z;     // 0..63
  const int t   = threadIdx.x;    // 0..255
  const int kv  = kvc * KVLEN + 4 * t;
  const float4* __restrict__ p = reinterpret_cast<const float4*>(
      A + ((size_t)bh * LQ + (size_t)qc * QLEN) * LKV + kv);

  double s0 = 0.0, s1 = 0.0, s2 = 0.0, s3 = 0.0, e = 0.0;
  for (int g = 0; g < QLEN; g += 16) {
    float fs0 = 0.f, fs1 = 0.f, fs2 = 0.f, fs3 = 0.f;
    float fe0 = 0.f, fe1 = 0.f, fe2 = 0.f, fe3 = 0.f;
#pragma unroll
    for (int qq = 0; qq < 16; ++qq) {
      float4 w = p[(size_t)(g + qq) * (LKV / 4)];
      fs0 += w.x; fs1 += w.y; fs2 += w.z; fs3 += w.w;
      fe0 = fmaf(w.x, fast_log2(w.x + 1e-8f), fe0);
      fe1 = fmaf(w.y, fast_log2(w.y + 1e-8f), fe1);
      fe2 = fmaf(w.z, fast_log2(w.z + 1e-8f), fe2);
      fe3 = fmaf(w.w, fast_log2(w.w + 1e-8f), fe3);
    }
    s0 += (double)fs0; s1 += (double)fs1; s2 += (double)fs2; s3 += (double)fs3;
    e += ((double)fe0 + (double)fe1) + ((double)fe2 + (double)fe3);
  }
  double* sp = spart + (size_t)(qc * BH + bh) * LKV + kv;
  sp[0] = s0; sp[1] = s1; sp[2] = s2; sp[3] = s3;

  __shared__ double red[256];
  red[t] = e;
  __syncthreads();
  for (int off = 128; off > 0; off >>= 1) {
    if (t < off) red[t] += red[t + off];
    __syncthreads();
  }
  if (t == 0) epart[(size_t)bh * (QCH * KVCH) + qc * KVCH + kvc] = red[0];
}

// head_entropy -> budgets -> k per (b,h). Half-even rint, Python floor-div.
__global__ __launch_bounds__(64) void budget_kernel(const double* __restrict__ epart,
                                                    int* __restrict__ kvals) {
  __shared__ double he[BH];
  __shared__ int bud[H_];
  const int t = threadIdx.x;  // 0..63 = bh
  double s = 0.0;
  for (int p = 0; p < QCH * KVCH; ++p) s += epart[(size_t)t * (QCH * KVCH) + p];
  he[t] = (-0.6931471805599453 * s) / (double)LQ;
  __syncthreads();
  if (t == 0) {
    for (int b = 0; b < B_; ++b) {
      double S = 0.0;
      for (int h = 0; h < H_; ++h) S += he[b * H_ + h];
      S += 1e-8;
      long long sum = 0;
      for (int h = 0; h < H_; ++h) {
        double x = he[b * H_ + h] / S * (double)TOTAL_BUDGET;
        int v = (int)rint(x);
        if (v < MINB) v = MINB;
        bud[h] = v; sum += v;
      }
      long long diff = (long long)TOTAL_BUDGET - sum;
      long long ph = (diff >= 0) ? diff / H_ : -((-diff + H_ - 1) / H_);
      long long rem = diff - ph * H_;
      for (int h = 0; h < H_; ++h) {
        long long v = (long long)bud[h] + ph + ((h < rem) ? 1 : 0);
        if (v < 1) v = 1;
        if (v > MID) v = MID;
        kvals[b * H_ + h] = (int)v;
      }
    }
  }
}

// Fused reduce + stable-descending rank + threshold + mask write (conflict-free).
// Block (jc, bh), jc in 0..3: builds s[0..MID) in LDS (fixed-order f64 sum of
// QCH spart partials; spart is 4MB -> L2/L3-resident, 4x redundant read ~free),
// then each thread ranks up to 2 j-slots via a broadcast-only i-scan (same LDS
// addr across all lanes -> no bank conflicts).
// rank(j) = #{i: s_i > s_j} + #{i<j: s_i == s_j}; keep iff rank < k.
__global__ __launch_bounds__(256) void countmask_kernel(const double* __restrict__ spart,
                                                        const int* __restrict__ kvals,
                                                        int* __restrict__ out) {
  const int jc = blockIdx.x, bh = blockIdx.y, t = threadIdx.x;
  __shared__ double s[MID];
  for (int m = t; m < MID; m += 256) {
    double v = 0.0;
    for (int qc = 0; qc < QCH; ++qc)
      v += spart[(size_t)(qc * BH + bh) * LKV + SINKN + m];
    s[m] = v;
  }
  __syncthreads();
  const int j0 = jc * JW + t;            // max 3*495+255 = 1740 < MID
  const int j1 = j0 + 256;               // valid if t < JW-256 = 239
  const bool has1 = (t < JW - 256);
  const double k0 = s[j0];
  const double k1 = has1 ? s[j1] : 0.0;
  unsigned c0 = 0, c1 = 0;
  for (int i = 0; i < MID; ++i) {
    const double si = s[i];
    c0 += (si > k0) ? 1u : 0u;
    c0 += ((si == k0) && (i < j0)) ? 1u : 0u;
    c1 += (si > k1) ? 1u : 0u;
    c1 += ((si == k1) && (i < j1)) ? 1u : 0u;
  }
  const unsigned k = (unsigned)kvals[bh];
  out[(size_t)bh * LKV + SINKN + j0] = (c0 < k) ? 1 : 0;
  if (has1) out[(size_t)bh * LKV + SINKN + j1] = (c1 < k) ? 1 : 0;
  if (jc == 0) {
    if (t < SINKN)   out[(size_t)bh * LKV + t] = 1;
    if (t < RECENTN) out[(size_t)bh * LKV + (LKV - RECENTN) + t] = 1;
  }
}

extern "C" void kernel_launch(void* const* d_in, const int* in_sizes, int n_in,
                              void* d_out, int out_size, void* d_ws, size_t ws_size,
                              hipStream_t stream) {
  const float* A = (const float*)d_in[0];
  int* out = (int*)d_out;

  // ws: spart[QCH*64*2048 f64]=4MB | epart[64*QCH*KVCH f64] | kvals[64 int]
  double* spart = (double*)d_ws;
  double* epart = spart + (size_t)QCH * BH * LKV;
  int* kvals = (int*)(epart + (size_t)BH * QCH * KVCH);

  stats_kernel<<<dim3(KVCH, QCH, BH), 256, 0, stream>>>(A, spart, epart);
  budget_kernel<<<1, 64, 0, stream>>>(epart, kvals);
  countmask_kernel<<<dim3(4, BH), 256, 0, stream>>>(spart, kvals, out);
}

// Round 10
// 278.047 us; speedup vs baseline: 1.1926x; 1.0102x over previous
//
#include <hip/hip_runtime.h>

// (B,H,Lq,Lkv) = (2,32,2048,2048), KEEP_RATIO=0.5, SINK=4, RECENT=64, ALPHA=0.2
#define B_   2
#define H_   32
#define BH   64
#define LQ   2048
#define LKV  2048
#define SINKN   4
#define RECENTN 64
#define MID  1980                              // LKV - SINK - RECENT
#define TOTAL_BUDGET 30592                     // (1024-68)*32
#define MINB 198                               // int(1980*0.5*0.2)
#define QCH  4                                 // q-chunks
#define KVCH 2
#define KVLEN (LKV / KVCH)                     // 1024 cols per block
#define QLEN (LQ / QCH)                        // 512 rows per block
#define TROWS 4                                // rows per LDS tile
#define NT   (QLEN / TROWS)                    // 128 tiles
#define JW   495                               // MID/4, j-window per countmask block

// Native v_log_f32 (log2, ~2^-21 rel err) — accuracy-safe (R3-R9 all absmax 0).
static __device__ __forceinline__ float fast_log2(float x) {
#if defined(__has_builtin) && __has_builtin(__builtin_amdgcn_logf)
  return __builtin_amdgcn_logf(x);
#else
  float r; asm volatile("v_log_f32 %0, %1" : "=v"(r) : "v"(x)); return r;
#endif
}

// Issue one 4-row tile via global_load_lds (HBM -> LDS, no VGPR return).
// ldsbase is wave-uniform (HW adds lane*16B). One wave covers 1KB of each 4KB row.
static __device__ __forceinline__ void issue_tile(const float* base, int tile,
                                                  float* ldsbase, int laneoff) {
#pragma unroll
  for (int r = 0; r < TROWS; ++r) {
    const float* g = base + (size_t)(tile * TROWS + r) * LKV + laneoff;
    __builtin_amdgcn_global_load_lds(
        (const __attribute__((address_space(1))) void*)g,
        (__attribute__((address_space(3))) void*)(ldsbase + r * 1024),
        16, 0, 0);
  }
}

// Stats pass: R9 tile topology (block (kvc,qc,bh): 1024 cols x 512 rows; thread
// owns cols 4t..4t+3), but the HBM read goes through global_load_lds staging
// with a barrier-FREE double-buffered pipeline: wave w loads bytes
// [w*1024,(w+1)*1024) of each row-chunk and reads back exactly that quarter
// (col-map == lane-map), so waves self-sync on counted vmcnt only.
// f32 group-of-16-rows accumulation folded into f64 (bit-identical to R9).
__global__ __launch_bounds__(256) void stats_kernel(const float* __restrict__ A,
                                                    double* __restrict__ spart,
                                                    double* __restrict__ epart) {
  const int kvc = blockIdx.x;     // 0..KVCH-1
  const int qc  = blockIdx.y;     // 0..QCH-1
  const int bh  = blockIdx.z;     // 0..63
  const int t   = threadIdx.x;    // 0..255
  const int w   = t >> 6;         // wave 0..3

  __shared__ float lbuf[2][TROWS][1024];   // 32 KB double buffer
  __shared__ double red[256];

  const float* base = A + ((size_t)bh * LQ + (size_t)qc * QLEN) * LKV + kvc * KVLEN;
  const int laneoff = 4 * t;                 // = w*256 + lane*4 floats
  float* ldsw0 = &lbuf[0][0][w * 256];       // wave-uniform dests
  float* ldsw1 = &lbuf[1][0][w * 256];

  double s0 = 0.0, s1 = 0.0, s2 = 0.0, s3 = 0.0, e = 0.0;
  float fs0 = 0.f, fs1 = 0.f, fs2 = 0.f, fs3 = 0.f;
  float fe0 = 0.f, fe1 = 0.f, fe2 = 0.f, fe3 = 0.f;

  issue_tile(base, 0, ldsw0, laneoff);
  int buf = 0;
  for (int tile = 0; tile < NT; ++tile) {
    if (tile + 1 < NT) {
      issue_tile(base, tile + 1, (buf ? ldsw0 : ldsw1), laneoff);
      asm volatile("s_waitcnt vmcnt(4)" ::: "memory");  // current tile's 4 loads done
    } else {
      asm volatile("s_waitcnt vmcnt(0)" ::: "memory");
    }
#pragma unroll
    for (int r = 0; r < TROWS; ++r) {
      float4 wv = *reinterpret_cast<const float4*>(&lbuf[buf][r][4 * t]);
      fs0 += wv.x; fs1 += wv.y; fs2 += wv.z; fs3 += wv.w;
      fe0 = fmaf(wv.x, fast_log2(wv.x + 1e-8f), fe0);
      fe1 = fmaf(wv.y, fast_log2(wv.y + 1e-8f), fe1);
      fe2 = fmaf(wv.z, fast_log2(wv.z + 1e-8f), fe2);
      fe3 = fmaf(wv.w, fast_log2(wv.w + 1e-8f), fe3);
    }
    if ((tile & 3) == 3) {  // every 16 rows: fold f32 -> f64 (same order as R9)
      s0 += (double)fs0; s1 += (double)fs1; s2 += (double)fs2; s3 += (double)fs3;
      e += ((double)fe0 + (double)fe1) + ((double)fe2 + (double)fe3);
      fs0 = fs1 = fs2 = fs3 = 0.f;
      fe0 = fe1 = fe2 = fe3 = 0.f;
    }
    buf ^= 1;
  }

  double* sp = spart + (size_t)(qc * BH + bh) * LKV + kvc * KVLEN + 4 * t;
  sp[0] = s0; sp[1] = s1; sp[2] = s2; sp[3] = s3;

  red[t] = e;
  __syncthreads();
  for (int off = 128; off > 0; off >>= 1) {
    if (t < off) red[t] += red[t + off];
    __syncthreads();
  }
  if (t == 0) epart[(size_t)bh * (QCH * KVCH) + qc * KVCH + kvc] = red[0];
}

// Fused budget + reduce + stable-descending rank + mask write (2-launch pipeline).
// Block (jc, bh): every block redundantly computes its batch's budget allocation
// (exact _head_budgets semantics: half-even rint, Python floor-div), builds
// s[0..MID) in LDS (fixed-order f64 sum of QCH partials), then broadcast-only
// i-scan ranks 2 j-slots per thread. rank(j)=#{i: s_i>s_j}+#{i<j: s_i==s_j}.
__global__ __launch_bounds__(256) void countmask_kernel(const double* __restrict__ spart,
                                                        const double* __restrict__ epart,
                                                        const int* __restrict__,
                                                        int* __restrict__ out) {
  const int jc = blockIdx.x, bh = blockIdx.y, t = threadIdx.x;
  __shared__ double s[MID];
  __shared__ double he[H_];
  __shared__ int bud[H_];
  __shared__ int ksh;

  for (int m = t; m < MID; m += 256) {
    double v = 0.0;
    for (int qc = 0; qc < QCH; ++qc)
      v += spart[(size_t)(qc * BH + bh) * LKV + SINKN + m];
    s[m] = v;
  }
  const int b = bh >> 5;   // batch of this head
  if (t < H_) {
    double ss = 0.0;
    for (int p = 0; p < QCH * KVCH; ++p)
      ss += epart[(size_t)(b * H_ + t) * (QCH * KVCH) + p];
    he[t] = (-0.6931471805599453 * ss) / (double)LQ;
  }
  __syncthreads();
  if (t == 0) {
    double S = 0.0;
    for (int h = 0; h < H_; ++h) S += he[h];
    S += 1e-8;
    long long sum = 0;
    for (int h = 0; h < H_; ++h) {
      double x = he[h] / S * (double)TOTAL_BUDGET;
      int v = (int)rint(x);          // jnp.round = half-to-even
      if (v < MINB) v = MINB;
      bud[h] = v; sum += v;
    }
    long long diff = (long long)TOTAL_BUDGET - sum;
    long long ph = (diff >= 0) ? diff / H_ : -((-diff + H_ - 1) / H_);
    long long rem = diff - ph * H_;
    const int h = bh & 31;
    long long v = (long long)bud[h] + ph + ((h < rem) ? 1 : 0);
    if (v < 1) v = 1;
    if (v > MID) v = MID;
    ksh = (int)v;
  }
  __syncthreads();

  const int j0 = jc * JW + t;            // max 3*495+255 = 1740 < MID
  const int j1 = j0 + 256;               // valid if t < JW-256 = 239
  const bool has1 = (t < JW - 256);
  const double k0 = s[j0];
  const double k1 = has1 ? s[j1] : 0.0;
  unsigned c0 = 0, c1 = 0;
  for (int i = 0; i < MID; ++i) {
    const double si = s[i];
    c0 += (si > k0) ? 1u : 0u;
    c0 += ((si == k0) && (i < j0)) ? 1u : 0u;
    c1 += (si > k1) ? 1u : 0u;
    c1 += ((si == k1) && (i < j1)) ? 1u : 0u;
  }
  const unsigned k = (unsigned)ksh;
  out[(size_t)bh * LKV + SINKN + j0] = (c0 < k) ? 1 : 0;
  if (has1) out[(size_t)bh * LKV + SINKN + j1] = (c1 < k) ? 1 : 0;
  if (jc == 0) {
    if (t < SINKN)   out[(size_t)bh * LKV + t] = 1;
    if (t < RECENTN) out[(size_t)bh * LKV + (LKV - RECENTN) + t] = 1;
  }
}

extern "C" void kernel_launch(void* const* d_in, const int* in_sizes, int n_in,
                              void* d_out, int out_size, void* d_ws, size_t ws_size,
                              hipStream_t stream) {
  const float* A = (const float*)d_in[0];
  int* out = (int*)d_out;

  // ws: spart[QCH*64*2048 f64]=4MB | epart[64*QCH*KVCH f64]
  double* spart = (double*)d_ws;
  double* epart = spart + (size_t)QCH * BH * LKV;

  stats_kernel<<<dim3(KVCH, QCH, BH), 256, 0, stream>>>(A, spart, epart);
  countmask_kernel<<<dim3(4, BH), 256, 0, stream>>>(spart, epart, nullptr, out);
}